// Round 15
// baseline (17.449 us; speedup 1.0000x reference)
//
#include <hip/hip_runtime.h>

#define N 2048
#define BS 16
#define QG 256             // queries per (b,qg) group: 4 per lane
#define NQG (N / QG)       // 8 query groups
#define TS 1024            // targets per slice (half the batch)
#define NTS (N / TS)       // 2 target slices
#define WAVES 16
#define TPB (WAVES * 64)   // 1024 threads
#define TPW (TS / WAVES)   // 64 targets per wave
#define F4I (TPW / 4)      // 16 iterations of 4 targets

typedef float v2f __attribute__((ext_vector_type(2)));

// h = ng * x + h, packed over 2 targets (v_pk_fma_f32: 2 FMA/lane/inst).
#define PK_FMA(h, a, b) asm("v_pk_fma_f32 %0, %1, %2, %0" : "+v"(h) : "v"(a), "v"(b))

// Single dispatch, 256 blocks x 1024 thr = exactly 1 block/CU (LDS padded
// past 80 KB so HW cannot co-schedule 2 blocks on a CU). Block dispatch cost
// measured ~0.76 ns/block (R13 A/B), so 1024->256 blocks trims ~0.6 us; NTS
// drops 8->2 (128 elections instead of 512).
// Inner loop: R14's packed v_pk_fma_f32 + min3 folds (validated, -1.0 us).
// Handoff (validated R12): agent-scope atomic store/load for data;
// __syncthreads() drains vmcnt before counter bumps; atomicInc(p,K-1)
// poison-proof last-arrival election (elect old==K-2); NO __threadfence
// (whole-L2 writeback storms: 6x slowdown, R11).
__global__ __launch_bounds__(TPB) void addsloss_fused(
    const float* __restrict__ target,
    const float* __restrict__ mp,
    const int* __restrict__ idx,
    const float* __restrict__ H,
    float* __restrict__ wsmin,
    float* __restrict__ partial,
    unsigned int* __restrict__ cnt2,
    unsigned int* __restrict__ cnt,
    float* __restrict__ out)
{
    __shared__ __align__(16) float xs[TS], ys[TS], zs[TS], ss[TS];  // 16 KB
    __shared__ float  pmin[WAVES][QG];   // 16 KB
    __shared__ float  ps[WAVES];
    __shared__ int    elect;
    __shared__ float  lds_pad[14336];    // pad block LDS > 80 KB => 1 block/CU

    const int bid  = blockIdx.x;
    const int b    = bid >> 4;        // / (NQG*NTS) = /16
    const int rem  = bid & 15;
    const int qg   = rem >> 1;        // / NTS
    const int ts   = rem & 1;         // % NTS
    const int tid  = threadIdx.x;
    const int wave = tid >> 6;
    const int lane = tid & 63;

    const int  cls = idx[b];
    const bool sym = (cls >= 0) && (cls <= 3);

    const float* tb = target + (size_t)b * N * 3;
    const float* mb = mp     + (size_t)b * N * 3;
    const float* hb = H      + b * 16;

    // keep the pad alive so the compiler doesn't drop the allocation
    if (tid == 0xffffffff) lds_pad[0] = 0.0f;

    float d = 0.0f;   // this thread's per-query distance (phase 2, tid<QG)

    if (sym) {
        // ---- Phase 1: stage 1024 targets SoA, one per thread ----
        {
            const int t = ts * TS + tid;
            const float x = tb[t * 3 + 0];
            const float y = tb[t * 3 + 1];
            const float z = tb[t * 3 + 2];
            xs[tid] = x; ys[tid] = y; zs[tid] = z;
            ss[tid] = x * x + y * y + z * z;
        }

        // 4 queries per lane; broadcast -2*tf into packed pairs.
        v2f ngx[4], ngy[4], ngz[4];
        #pragma unroll
        for (int qi = 0; qi < 4; ++qi) {
            const int q = qg * QG + qi * 64 + lane;
            const float m0 = mb[q * 3 + 0];
            const float m1 = mb[q * 3 + 1];
            const float m2 = mb[q * 3 + 2];
            const float gx = -2.0f * (hb[0] * m0 + hb[1]  * m1 + hb[2]  * m2 + hb[3]);
            const float gy = -2.0f * (hb[4] * m0 + hb[5]  * m1 + hb[6]  * m2 + hb[7]);
            const float gz = -2.0f * (hb[8] * m0 + hb[9]  * m1 + hb[10] * m2 + hb[11]);
            ngx[qi] = (v2f){gx, gx};
            ngy[qi] = (v2f){gy, gy};
            ngz[qi] = (v2f){gz, gz};
        }

        __syncthreads();

        // This wave scans targets [wave*64, wave*64+64), 4 per iteration.
        const float4* x4 = reinterpret_cast<const float4*>(xs) + wave * F4I;
        const float4* y4 = reinterpret_cast<const float4*>(ys) + wave * F4I;
        const float4* z4 = reinterpret_cast<const float4*>(zs) + wave * F4I;
        const float4* s4 = reinterpret_cast<const float4*>(ss) + wave * F4I;

        float acc[4][2];
        #pragma unroll
        for (int qi = 0; qi < 4; ++qi) { acc[qi][0] = 3.4e38f; acc[qi][1] = 3.4e38f; }

        #pragma unroll 4
        for (int j = 0; j < F4I; ++j) {
            const float4 X = x4[j], Y = y4[j], Z = z4[j], S = s4[j];
            const v2f Xlo = {X.x, X.y}, Xhi = {X.z, X.w};
            const v2f Ylo = {Y.x, Y.y}, Yhi = {Y.z, Y.w};
            const v2f Zlo = {Z.x, Z.y}, Zhi = {Z.z, Z.w};
            const v2f Slo = {S.x, S.y}, Shi = {S.z, S.w};
            #pragma unroll
            for (int qi = 0; qi < 4; ++qi) {
                v2f h0 = Slo, h1 = Shi;
                PK_FMA(h0, ngx[qi], Xlo);
                PK_FMA(h1, ngx[qi], Xhi);
                PK_FMA(h0, ngy[qi], Ylo);
                PK_FMA(h1, ngy[qi], Yhi);
                PK_FMA(h0, ngz[qi], Zlo);
                PK_FMA(h1, ngz[qi], Zhi);
                acc[qi][0] = fminf(fminf(h0.x, h0.y), acc[qi][0]);  // v_min3
                acc[qi][1] = fminf(fminf(h1.x, h1.y), acc[qi][1]);
            }
        }

        #pragma unroll
        for (int qi = 0; qi < 4; ++qi)
            pmin[wave][qi * 64 + lane] = fminf(acc[qi][0], acc[qi][1]);
        __syncthreads();

        // Combine 16 waves, publish this slice's per-query min (agent-scope).
        if (tid < QG) {
            float m = pmin[0][tid];
            #pragma unroll
            for (int w = 1; w < WAVES; ++w) m = fminf(m, pmin[w][tid]);
            __hip_atomic_store(&wsmin[((size_t)(b * NTS + ts)) * N + qg * QG + tid],
                               m, __ATOMIC_RELAXED, __HIP_MEMORY_SCOPE_AGENT);
        }

        // ---- Election: last of the 2 slice-blocks of this (b,qg) ----
        __syncthreads();   // s_waitcnt vmcnt(0) before barrier: publishes done
        if (tid == 0) {
            const unsigned int old = atomicInc(&cnt2[b * NQG + qg], NTS - 1);
            elect = (old == NTS - 2) ? 1 : 0;   // last arrival
        }
        __syncthreads();
        if (!elect) return;

        // ---- Phase 2: q = qg*QG + tid (tid < QG) ----
        if (tid < QG) {
            const int q = qg * QG + tid;
            float m = fminf(
                __hip_atomic_load(&wsmin[((size_t)(b * NTS + 0)) * N + q],
                                  __ATOMIC_RELAXED, __HIP_MEMORY_SCOPE_AGENT),
                __hip_atomic_load(&wsmin[((size_t)(b * NTS + 1)) * N + q],
                                  __ATOMIC_RELAXED, __HIP_MEMORY_SCOPE_AGENT));
            const float m0 = mb[q * 3 + 0];
            const float m1 = mb[q * 3 + 1];
            const float m2 = mb[q * 3 + 2];
            const float fx = hb[0] * m0 + hb[1]  * m1 + hb[2]  * m2 + hb[3];
            const float fy = hb[4] * m0 + hb[5]  * m1 + hb[6]  * m2 + hb[7];
            const float fz = hb[8] * m0 + hb[9]  * m1 + hb[10] * m2 + hb[11];
            const float c = fx * fx + fy * fy + fz * fz;
            d = sqrtf(fmaxf(0.0f, c + m));
        }
    } else {
        if (ts != 0) return;   // one block per (b,qg) does the direct path
        if (tid < QG) {
            const int q = qg * QG + tid;
            const float m0 = mb[q * 3 + 0];
            const float m1 = mb[q * 3 + 1];
            const float m2 = mb[q * 3 + 2];
            const float fx = hb[0] * m0 + hb[1]  * m1 + hb[2]  * m2 + hb[3];
            const float fy = hb[4] * m0 + hb[5]  * m1 + hb[6]  * m2 + hb[7];
            const float fz = hb[8] * m0 + hb[9]  * m1 + hb[10] * m2 + hb[11];
            const float dx = fx - tb[q * 3 + 0];
            const float dy = fy - tb[q * 3 + 1];
            const float dz = fz - tb[q * 3 + 2];
            d = sqrtf(dx * dx + dy * dy + dz * dz);
        }
    }

    // ---- Fixed-order block sum (tid>=QG contribute 0) -> partial[b][qg] ----
    #pragma unroll
    for (int off = 32; off > 0; off >>= 1) d += __shfl_down(d, off);
    if (lane == 0) ps[wave] = d;
    __syncthreads();
    if (tid == 0) {
        float s = 0.0f;
        #pragma unroll
        for (int w = 0; w < WAVES; ++w) s += ps[w];
        __hip_atomic_store(&partial[b * NQG + qg], s,
                           __ATOMIC_RELAXED, __HIP_MEMORY_SCOPE_AGENT);
        // Ensure the partial store completed at L3 before bumping the counter.
        asm volatile("s_waitcnt vmcnt(0)" ::: "memory");
        const unsigned int old = atomicInc(&cnt[b], NQG - 1);
        if (old == NQG - 2) {               // 8th (last) group of this batch
            float tot = 0.0f;
            #pragma unroll
            for (int p = 0; p < NQG; ++p)
                tot += __hip_atomic_load(&partial[b * NQG + p],
                                         __ATOMIC_RELAXED, __HIP_MEMORY_SCOPE_AGENT);
            out[b] = tot * (1.0f / (float)N);
        }
    }
}

extern "C" void kernel_launch(void* const* d_in, const int* in_sizes, int n_in,
                              void* d_out, int out_size, void* d_ws, size_t ws_size,
                              hipStream_t stream) {
    const float* target = (const float*)d_in[0];   // [16, 2048, 3]
    const float* mp     = (const float*)d_in[1];   // [16, 2048, 3]
    const int*   idx    = (const int*)  d_in[2];   // [16, 1]
    const float* H      = (const float*)d_in[3];   // [16, 4, 4]
    float*       out    = (float*)d_out;           // [16]

    char* ws = (char*)d_ws;
    float*        wsmin   = (float*)ws;                              // 256 KB
    float*        partial = (float*)(ws + (size_t)BS * NTS * N * 4); // 128 f
    unsigned int* cnt2    = (unsigned int*)((char*)partial + 512);   // 128 u
    unsigned int* cnt     = (unsigned int*)((char*)cnt2 + 512);      // 16 u

    addsloss_fused<<<BS * NQG * NTS, TPB, 0, stream>>>(
        target, mp, idx, H, wsmin, partial, cnt2, cnt, out);
}